// Round 1
// baseline (1617.407 us; speedup 1.0000x reference)
//
#include <hip/hip_runtime.h>
#include <math.h>

#define NEG_SLOPE 0.2f

// ---- monotone float<->uint encoding for atomicMax on floats ----
__device__ __forceinline__ unsigned enc_f(float f) {
    unsigned u = __float_as_uint(f);
    return (u & 0x80000000u) ? ~u : (u | 0x80000000u);
}
__device__ __forceinline__ float dec_f(unsigned u) {
    return (u & 0x80000000u) ? __uint_as_float(u ^ 0x80000000u) : __uint_as_float(~u);
}

__device__ __forceinline__ void edge_sd(const int* __restrict__ ei, int E, int e, int& s, int& d) {
    if (e < E) { s = ei[e]; d = ei[E + e]; }
    else { s = e - E; d = s; }  // self-loop
}

// ---- Layer 1: h1 = x @ W1 ; alpha_src/dst per (node, head) ----
// one block (512 thr) per node; wave w == head w (64 lanes == 64 channels)
__global__ __launch_bounds__(512) void k_gemm1(
    const float* __restrict__ x, const float* __restrict__ W1,
    const float* __restrict__ a_src, const float* __restrict__ a_dst,
    float* __restrict__ h1, float* __restrict__ asrc, float* __restrict__ adst)
{
    int n = blockIdx.x;
    int t = threadIdx.x;
    __shared__ float xs[64];
    if (t < 64) xs[t] = x[n * 64 + t];
    __syncthreads();
    float v = 0.f;
#pragma unroll
    for (int k = 0; k < 64; ++k) v += xs[k] * W1[k * 512 + t];
    h1[(size_t)n * 512 + t] = v;
    float s = v * a_src[t];
    float d = v * a_dst[t];
#pragma unroll
    for (int off = 32; off > 0; off >>= 1) {
        s += __shfl_xor(s, off, 64);
        d += __shfl_xor(d, off, 64);
    }
    if ((t & 63) == 0) {
        int head = t >> 6;
        asrc[n * 8 + head] = s;
        adst[n * 8 + head] = d;
    }
}

// ---- edge max (layer1): per (edge, head) ----
__global__ void k_max1(const int* __restrict__ ei, int E, int Etot,
                       const float* __restrict__ asrc, const float* __restrict__ adst,
                       unsigned* __restrict__ mx)
{
    int i = blockIdx.x * blockDim.x + threadIdx.x;
    if (i >= Etot * 8) return;
    int e = i >> 3, h = i & 7;
    int s, d; edge_sd(ei, E, e, s, d);
    float el = asrc[s * 8 + h] + adst[d * 8 + h];
    el = el >= 0.f ? el : NEG_SLOPE * el;
    atomicMax(&mx[d * 8 + h], enc_f(el));
}

// ---- edge denom (layer1) ----
__global__ void k_den1(const int* __restrict__ ei, int E, int Etot,
                       const float* __restrict__ asrc, const float* __restrict__ adst,
                       const unsigned* __restrict__ mx, float* __restrict__ den)
{
    int i = blockIdx.x * blockDim.x + threadIdx.x;
    if (i >= Etot * 8) return;
    int e = i >> 3, h = i & 7;
    int s, d; edge_sd(ei, E, e, s, d);
    float el = asrc[s * 8 + h] + adst[d * 8 + h];
    el = el >= 0.f ? el : NEG_SLOPE * el;
    float p = expf(el - dec_f(mx[d * 8 + h]));
    atomicAdd(&den[d * 8 + h], p);
}

// ---- per-edge alpha (layer1) ----
__global__ void k_alpha1(const int* __restrict__ ei, int E, int Etot,
                         const float* __restrict__ asrc, const float* __restrict__ adst,
                         const unsigned* __restrict__ mx, const float* __restrict__ den,
                         float* __restrict__ aE)
{
    int i = blockIdx.x * blockDim.x + threadIdx.x;
    if (i >= Etot * 8) return;
    int e = i >> 3, h = i & 7;
    int s, d; edge_sd(ei, E, e, s, d);
    float el = asrc[s * 8 + h] + adst[d * 8 + h];
    el = el >= 0.f ? el : NEG_SLOPE * el;
    float p = expf(el - dec_f(mx[d * 8 + h]));
    aE[(size_t)e * 8 + h] = p / (den[d * 8 + h] + 1e-16f);
}

// ---- scatter aggregate (layer1): per (edge, col) ----
__global__ void k_agg1(const int* __restrict__ ei, int E, int Etot,
                       const float* __restrict__ aE, const float* __restrict__ h1,
                       float* __restrict__ acc)
{
    long long i = (long long)blockIdx.x * blockDim.x + threadIdx.x;
    if (i >= (long long)Etot * 512) return;
    int e = (int)(i >> 9);
    int col = (int)(i & 511);
    int h = col >> 6;
    int s, d; edge_sd(ei, E, e, s, d);
    float val = aE[(size_t)e * 8 + h] * h1[(size_t)s * 512 + col];
    atomicAdd(&acc[(size_t)d * 512 + col], val);
}

// ---- finalize layer1: y = elu(acc + b1), in-place ----
__global__ void k_fin1(float* __restrict__ acc, const float* __restrict__ b1, int N)
{
    long long i = (long long)blockIdx.x * blockDim.x + threadIdx.x;
    if (i >= (long long)N * 512) return;
    float v = acc[i] + b1[i & 511];
    acc[i] = v > 0.f ? v : expf(v) - 1.f;
}

// ---- layer2 gemm: h2 = y @ W2  (one thread per (n,c)) ----
__global__ void k_gemm2(const float* __restrict__ y, const float* __restrict__ W2,
                        float* __restrict__ h2, int N)
{
    int i = blockIdx.x * blockDim.x + threadIdx.x;
    if (i >= N * 17) return;
    int n = i / 17, c = i % 17;
    float acc = 0.f;
    const float* yr = y + (size_t)n * 512;
    for (int k = 0; k < 512; ++k) acc += yr[k] * W2[k * 17 + c];
    h2[i] = acc;
}

// ---- layer2 per-node alpha ----
__global__ void k_alpha2n(const float* __restrict__ h2,
                          const float* __restrict__ a_src, const float* __restrict__ a_dst,
                          float* __restrict__ asrc, float* __restrict__ adst, int N)
{
    int n = blockIdx.x * blockDim.x + threadIdx.x;
    if (n >= N) return;
    float s = 0.f, d = 0.f;
#pragma unroll
    for (int c = 0; c < 17; ++c) {
        float v = h2[n * 17 + c];
        s += v * a_src[c];
        d += v * a_dst[c];
    }
    asrc[n] = s; adst[n] = d;
}

__global__ void k_max2(const int* __restrict__ ei, int E, int Etot,
                       const float* __restrict__ asrc, const float* __restrict__ adst,
                       unsigned* __restrict__ mx)
{
    int e = blockIdx.x * blockDim.x + threadIdx.x;
    if (e >= Etot) return;
    int s, d; edge_sd(ei, E, e, s, d);
    float el = asrc[s] + adst[d];
    el = el >= 0.f ? el : NEG_SLOPE * el;
    atomicMax(&mx[d], enc_f(el));
}

__global__ void k_den2(const int* __restrict__ ei, int E, int Etot,
                       const float* __restrict__ asrc, const float* __restrict__ adst,
                       const unsigned* __restrict__ mx, float* __restrict__ den)
{
    int e = blockIdx.x * blockDim.x + threadIdx.x;
    if (e >= Etot) return;
    int s, d; edge_sd(ei, E, e, s, d);
    float el = asrc[s] + adst[d];
    el = el >= 0.f ? el : NEG_SLOPE * el;
    atomicAdd(&den[d], expf(el - dec_f(mx[d])));
}

__global__ void k_alpha2e(const int* __restrict__ ei, int E, int Etot,
                          const float* __restrict__ asrc, const float* __restrict__ adst,
                          const unsigned* __restrict__ mx, const float* __restrict__ den,
                          float* __restrict__ aE)
{
    int e = blockIdx.x * blockDim.x + threadIdx.x;
    if (e >= Etot) return;
    int s, d; edge_sd(ei, E, e, s, d);
    float el = asrc[s] + adst[d];
    el = el >= 0.f ? el : NEG_SLOPE * el;
    float p = expf(el - dec_f(mx[d]));
    aE[e] = p / (den[d] + 1e-16f);
}

__global__ void k_agg2(const int* __restrict__ ei, int E, int Etot,
                       const float* __restrict__ aE, const float* __restrict__ h2,
                       float* __restrict__ acc)
{
    int i = blockIdx.x * blockDim.x + threadIdx.x;
    if (i >= Etot * 17) return;
    int e = i / 17, c = i % 17;
    int s, d; edge_sd(ei, E, e, s, d);
    atomicAdd(&acc[d * 17 + c], aE[e] * h2[s * 17 + c]);
}

// ---- final: out = log_softmax(acc2 + b2) ----
__global__ void k_final(const float* __restrict__ acc, const float* __restrict__ b2,
                        float* __restrict__ out, int N)
{
    int n = blockIdx.x * blockDim.x + threadIdx.x;
    if (n >= N) return;
    float l[17];
    float m = -1e30f;
#pragma unroll
    for (int c = 0; c < 17; ++c) {
        l[c] = acc[n * 17 + c] + b2[c];
        m = fmaxf(m, l[c]);
    }
    float s = 0.f;
#pragma unroll
    for (int c = 0; c < 17; ++c) s += expf(l[c] - m);
    float lg = logf(s);
#pragma unroll
    for (int c = 0; c < 17; ++c) out[n * 17 + c] = l[c] - m - lg;
}

extern "C" void kernel_launch(void* const* d_in, const int* in_sizes, int n_in,
                              void* d_out, int out_size, void* d_ws, size_t ws_size,
                              hipStream_t stream)
{
    const float* x     = (const float*)d_in[0];
    const int*   ei    = (const int*)d_in[1];
    const float* W1    = (const float*)d_in[2];
    const float* asrc1w= (const float*)d_in[3];
    const float* adst1w= (const float*)d_in[4];
    const float* b1    = (const float*)d_in[5];
    const float* W2    = (const float*)d_in[6];
    const float* asrc2w= (const float*)d_in[7];
    const float* adst2w= (const float*)d_in[8];
    const float* b2    = (const float*)d_in[9];
    float* out = (float*)d_out;

    const int N = in_sizes[0] / 64;
    const int E = in_sizes[1] / 2;
    const int Etot = N + E;

    // workspace layout (floats)
    float* ws = (float*)d_ws;
    size_t o = 0;
    float*    h1    = ws + o; o += (size_t)N * 512;
    float*    acc1  = ws + o; o += (size_t)N * 512;
    float*    asrc1 = ws + o; o += (size_t)N * 8;
    float*    adst1 = ws + o; o += (size_t)N * 8;
    unsigned* max1  = (unsigned*)(ws + o); o += (size_t)N * 8;
    float*    den1  = ws + o; o += (size_t)N * 8;
    float*    aE1   = ws + o; o += (size_t)Etot * 8;
    float*    h2    = ws + o; o += (size_t)N * 17;
    float*    acc2  = ws + o; o += (size_t)N * 17;
    float*    asrc2 = ws + o; o += (size_t)N;
    float*    adst2 = ws + o; o += (size_t)N;
    unsigned* max2  = (unsigned*)(ws + o); o += (size_t)N;
    float*    den2  = ws + o; o += (size_t)N;
    float*    aE2   = ws + o; o += (size_t)Etot;

    // zero accumulators / maxes / denoms
    hipMemsetAsync(acc1, 0, (size_t)N * 512 * 4, stream);
    hipMemsetAsync(max1, 0, (size_t)N * 8 * 4, stream);
    hipMemsetAsync(den1, 0, (size_t)N * 8 * 4, stream);
    hipMemsetAsync(acc2, 0, (size_t)N * 17 * 4, stream);
    hipMemsetAsync(max2, 0, (size_t)N * 4, stream);
    hipMemsetAsync(den2, 0, (size_t)N * 4, stream);

    // layer 1
    k_gemm1<<<N, 512, 0, stream>>>(x, W1, asrc1w, adst1w, h1, asrc1, adst1);
    {
        int tot = Etot * 8, blk = 256, g = (tot + blk - 1) / blk;
        k_max1<<<g, blk, 0, stream>>>(ei, E, Etot, asrc1, adst1, max1);
        k_den1<<<g, blk, 0, stream>>>(ei, E, Etot, asrc1, adst1, max1, den1);
        k_alpha1<<<g, blk, 0, stream>>>(ei, E, Etot, asrc1, adst1, max1, den1, aE1);
    }
    {
        long long tot = (long long)Etot * 512; int blk = 256;
        long long g = (tot + blk - 1) / blk;
        k_agg1<<<(unsigned)g, blk, 0, stream>>>(ei, E, Etot, aE1, h1, acc1);
    }
    {
        long long tot = (long long)N * 512; int blk = 256;
        long long g = (tot + blk - 1) / blk;
        k_fin1<<<(unsigned)g, blk, 0, stream>>>(acc1, b1, N);
    }

    // layer 2
    {
        int tot = N * 17, blk = 256, g = (tot + blk - 1) / blk;
        k_gemm2<<<g, blk, 0, stream>>>(acc1, W2, h2, N);
    }
    {
        int blk = 256, g = (N + blk - 1) / blk;
        k_alpha2n<<<g, blk, 0, stream>>>(h2, asrc2w, adst2w, asrc2, adst2, N);
    }
    {
        int blk = 256, g = (Etot + blk - 1) / blk;
        k_max2<<<g, blk, 0, stream>>>(ei, E, Etot, asrc2, adst2, max2);
        k_den2<<<g, blk, 0, stream>>>(ei, E, Etot, asrc2, adst2, max2, den2);
        k_alpha2e<<<g, blk, 0, stream>>>(ei, E, Etot, asrc2, adst2, max2, den2, aE2);
    }
    {
        int tot = Etot * 17, blk = 256, g = (tot + blk - 1) / blk;
        k_agg2<<<g, blk, 0, stream>>>(ei, E, Etot, aE2, h2, acc2);
    }
    {
        int blk = 256, g = (N + blk - 1) / blk;
        k_final<<<g, blk, 0, stream>>>(acc2, b2, out, N);
    }
}

// Round 2
// 789.052 us; speedup vs baseline: 2.0498x; 2.0498x over previous
//
#include <hip/hip_runtime.h>
#include <math.h>

#define NEG_SLOPE 0.2f

__device__ __forceinline__ void edge_sd(const int* __restrict__ ei, int E, int e, int& s, int& d) {
    if (e < E) { s = ei[e]; d = ei[E + e]; }
    else { s = e - E; d = s; }  // self-loop
}

// ================= CSR build =================
__global__ void k_hist(const int* __restrict__ ei, int E, int Etot, int* __restrict__ deg)
{
    int e = blockIdx.x * blockDim.x + threadIdx.x;
    if (e >= Etot) return;
    int s, d; edge_sd(ei, E, e, s, d);
    atomicAdd(&deg[d], 1);
}

__global__ __launch_bounds__(1024) void k_scan(const int* __restrict__ deg,
                                               int* __restrict__ rs, int N)
{
    __shared__ int part[1024];
    int t = threadIdx.x;
    int chunk = (N + 1023) >> 10;
    int b = t * chunk, e = min(b + chunk, N);
    int s = 0;
    for (int i = b; i < e; ++i) s += deg[i];
    part[t] = s;
    __syncthreads();
    for (int off = 1; off < 1024; off <<= 1) {
        int v = (t >= off) ? part[t - off] : 0;
        __syncthreads();
        part[t] += v;
        __syncthreads();
    }
    int excl = (t == 0) ? 0 : part[t - 1];
    for (int i = b; i < e; ++i) { rs[i] = excl; excl += deg[i]; }
    if (t == 1023) rs[N] = part[1023];
}

__global__ void k_fill(const int* __restrict__ ei, int E, int Etot,
                       const int* __restrict__ rs, int* __restrict__ cur,
                       int* __restrict__ csr_src)
{
    int e = blockIdx.x * blockDim.x + threadIdx.x;
    if (e >= Etot) return;
    int s, d; edge_sd(ei, E, e, s, d);
    int pos = rs[d] + atomicAdd(&cur[d], 1);
    csr_src[pos] = s;
}

// ================= Layer 1 =================
// GEMM1: 8 nodes per 512-thread block; fused per-head alpha dot products.
#define NPB 8
__global__ __launch_bounds__(512) void k_gemm1(
    const float* __restrict__ x, const float* __restrict__ W1,
    const float* __restrict__ a_src, const float* __restrict__ a_dst,
    float* __restrict__ h1, float* __restrict__ asrc, float* __restrict__ adst, int N)
{
    int n0 = blockIdx.x * NPB;
    int t = threadIdx.x;
    __shared__ float xs[NPB][64];
    {
        int m = t >> 6, k = t & 63;
        xs[m][k] = (n0 + m < N) ? x[(size_t)(n0 + m) * 64 + k] : 0.f;
    }
    __syncthreads();
    float acc[NPB];
#pragma unroll
    for (int m = 0; m < NPB; ++m) acc[m] = 0.f;
#pragma unroll 8
    for (int k = 0; k < 64; ++k) {
        float w = W1[k * 512 + t];
#pragma unroll
        for (int m = 0; m < NPB; ++m) acc[m] += xs[m][k] * w;
    }
    float aw_s = a_src[t], aw_d = a_dst[t];
    int head = t >> 6, lane = t & 63;
#pragma unroll
    for (int m = 0; m < NPB; ++m) {
        int n = n0 + m;
        if (n >= N) break;
        h1[(size_t)n * 512 + t] = acc[m];
        float s = acc[m] * aw_s, d = acc[m] * aw_d;
#pragma unroll
        for (int off = 1; off < 64; off <<= 1) {
            s += __shfl_xor(s, off, 64);
            d += __shfl_xor(d, off, 64);
        }
        if (lane == 0) { asrc[n * 8 + head] = s; adst[n * 8 + head] = d; }
    }
}

// Softmax layer1: one wave per node; lane = (edge-slot j0 = lane>>3, head h = lane&7)
__global__ __launch_bounds__(256) void k_sm1(
    const int* __restrict__ rs, const int* __restrict__ csr_src,
    const float* __restrict__ asrc, const float* __restrict__ adst,
    float* __restrict__ aE, int N)
{
    int node = blockIdx.x * 4 + (threadIdx.x >> 6);
    if (node >= N) return;
    int lane = threadIdx.x & 63;
    int h = lane & 7, j0 = lane >> 3;
    int base = rs[node], deg = rs[node + 1] - base;
    float ad = adst[node * 8 + h];
    float m = -1e30f;
    for (int j = j0; j < deg; j += 8) {
        int s = csr_src[base + j];
        float el = asrc[s * 8 + h] + ad;
        el = el >= 0.f ? el : NEG_SLOPE * el;
        m = fmaxf(m, el);
    }
    m = fmaxf(m, __shfl_xor(m, 8, 64));
    m = fmaxf(m, __shfl_xor(m, 16, 64));
    m = fmaxf(m, __shfl_xor(m, 32, 64));
    float sum = 0.f;
    for (int j = j0; j < deg; j += 8) {
        int s = csr_src[base + j];
        float el = asrc[s * 8 + h] + ad;
        el = el >= 0.f ? el : NEG_SLOPE * el;
        float p = expf(el - m);
        sum += p;
        aE[(size_t)(base + j) * 8 + h] = p;
    }
    sum += __shfl_xor(sum, 8, 64);
    sum += __shfl_xor(sum, 16, 64);
    sum += __shfl_xor(sum, 32, 64);
    float inv = 1.f / (sum + 1e-16f);
    for (int j = j0; j < deg; j += 8) aE[(size_t)(base + j) * 8 + h] *= inv;
}

// Aggregate layer1 (gather, no atomics) + bias + ELU
__global__ __launch_bounds__(512) void k_agg1(
    const int* __restrict__ rs, const int* __restrict__ csr_src,
    const float* __restrict__ aE, const float* __restrict__ h1,
    const float* __restrict__ b1, float* __restrict__ y, int N)
{
    int d = blockIdx.x;
    int col = threadIdx.x, h = col >> 6;
    int base = rs[d], end = rs[d + 1];
    float acc = 0.f;
    for (int p = base; p < end; ++p) {
        int s = csr_src[p];
        float a = aE[(size_t)p * 8 + h];
        acc += a * h1[(size_t)s * 512 + col];
    }
    float v = acc + b1[col];
    y[(size_t)d * 512 + col] = v > 0.f ? v : expf(v) - 1.f;
}

// ================= Layer 2 =================
// GEMM2: wave per node, W2 transposed into LDS (conflict-free), fused alpha dots.
__global__ __launch_bounds__(1024) void k_gemm2(
    const float* __restrict__ y, const float* __restrict__ W2,
    const float* __restrict__ a_src2, const float* __restrict__ a_dst2,
    float* __restrict__ h2, float* __restrict__ asrc, float* __restrict__ adst, int N)
{
    __shared__ float W2t[17][512];
    int t = threadIdx.x;
    for (int i = t; i < 512 * 17; i += 1024) {
        int k = i / 17, c = i % 17;
        W2t[c][k] = W2[i];
    }
    __syncthreads();
    int wave = t >> 6, lane = t & 63;
    int stride = gridDim.x * 16;
    for (int n = blockIdx.x * 16 + wave; n < N; n += stride) {
        const float* yr = y + (size_t)n * 512;
        float yk[8];
#pragma unroll
        for (int i = 0; i < 8; ++i) yk[i] = yr[i * 64 + lane];
        float acc[17];
#pragma unroll
        for (int c = 0; c < 17; ++c) {
            float a = 0.f;
#pragma unroll
            for (int i = 0; i < 8; ++i) a += yk[i] * W2t[c][i * 64 + lane];
            acc[c] = a;
        }
#pragma unroll
        for (int c = 0; c < 17; ++c) {
            float v = acc[c];
            v += __shfl_xor(v, 1, 64);  v += __shfl_xor(v, 2, 64);
            v += __shfl_xor(v, 4, 64);  v += __shfl_xor(v, 8, 64);
            v += __shfl_xor(v, 16, 64); v += __shfl_xor(v, 32, 64);
            acc[c] = v;
        }
        if (lane == 0) {
            float s = 0.f, d = 0.f;
#pragma unroll
            for (int c = 0; c < 17; ++c) {
                h2[(size_t)n * 17 + c] = acc[c];
                s += acc[c] * a_src2[c];
                d += acc[c] * a_dst2[c];
            }
            asrc[n] = s; adst[n] = d;
        }
    }
}

// Softmax layer2: one thread per node (deg ~11, tables are L2-resident)
__global__ void k_sm2(const int* __restrict__ rs, const int* __restrict__ csr_src,
                      const float* __restrict__ asrc, const float* __restrict__ adst,
                      float* __restrict__ alpha, int N)
{
    int d = blockIdx.x * blockDim.x + threadIdx.x;
    if (d >= N) return;
    int base = rs[d], end = rs[d + 1];
    float ad = adst[d];
    float m = -1e30f;
    for (int p = base; p < end; ++p) {
        float el = asrc[csr_src[p]] + ad;
        el = el >= 0.f ? el : NEG_SLOPE * el;
        m = fmaxf(m, el);
    }
    float sum = 0.f;
    for (int p = base; p < end; ++p) {
        float el = asrc[csr_src[p]] + ad;
        el = el >= 0.f ? el : NEG_SLOPE * el;
        float pw = expf(el - m);
        sum += pw;
        alpha[p] = pw;
    }
    float inv = 1.f / (sum + 1e-16f);
    for (int p = base; p < end; ++p) alpha[p] *= inv;
}

// Aggregate layer2 + bias + log_softmax: one wave per node, lanes 0..16 = channels
__global__ __launch_bounds__(256) void k_out(
    const int* __restrict__ rs, const int* __restrict__ csr_src,
    const float* __restrict__ alpha, const float* __restrict__ h2,
    const float* __restrict__ b2, float* __restrict__ out, int N)
{
    int node = blockIdx.x * 4 + (threadIdx.x >> 6);
    if (node >= N) return;
    int lane = threadIdx.x & 63;
    int base = rs[node], end = rs[node + 1];
    float acc = 0.f;
    if (lane < 17) {
        for (int p = base; p < end; ++p) {
            int s = csr_src[p];
            acc += alpha[p] * h2[(size_t)s * 17 + lane];
        }
    }
    float logit = (lane < 17) ? acc + b2[lane] : -1e30f;
    float m = logit;
#pragma unroll
    for (int off = 1; off < 64; off <<= 1) m = fmaxf(m, __shfl_xor(m, off, 64));
    float p = (lane < 17) ? expf(logit - m) : 0.f;
    float ssum = p;
#pragma unroll
    for (int off = 1; off < 64; off <<= 1) ssum += __shfl_xor(ssum, off, 64);
    if (lane < 17) out[(size_t)node * 17 + lane] = logit - m - logf(ssum);
}

extern "C" void kernel_launch(void* const* d_in, const int* in_sizes, int n_in,
                              void* d_out, int out_size, void* d_ws, size_t ws_size,
                              hipStream_t stream)
{
    const float* x      = (const float*)d_in[0];
    const int*   ei     = (const int*)d_in[1];
    const float* W1     = (const float*)d_in[2];
    const float* asrc1w = (const float*)d_in[3];
    const float* adst1w = (const float*)d_in[4];
    const float* b1     = (const float*)d_in[5];
    const float* W2     = (const float*)d_in[6];
    const float* asrc2w = (const float*)d_in[7];
    const float* adst2w = (const float*)d_in[8];
    const float* b2     = (const float*)d_in[9];
    float* out = (float*)d_out;

    const int N = in_sizes[0] / 64;
    const int E = in_sizes[1] / 2;
    const int Etot = N + E;

    // workspace layout
    float* ws = (float*)d_ws;
    size_t o = 0;
    float* h1    = ws + o; o += (size_t)N * 512;
    float* y     = ws + o; o += (size_t)N * 512;
    float* asrc1 = ws + o; o += (size_t)N * 8;
    float* adst1 = ws + o; o += (size_t)N * 8;
    float* aE1   = ws + o; o += (size_t)Etot * 8;
    float* h2    = ws + o; o += (size_t)N * 17;
    float* asrc2 = ws + o; o += (size_t)N;
    float* adst2 = ws + o; o += (size_t)N;
    float* aE2   = ws + o; o += (size_t)Etot;
    int* deg     = (int*)(ws + o); o += (size_t)N;
    int* cur     = (int*)(ws + o); o += (size_t)N;
    int* rs      = (int*)(ws + o); o += (size_t)N + 1;
    int* csr_src = (int*)(ws + o); o += (size_t)Etot;

    hipMemsetAsync(deg, 0, (size_t)N * 4, stream);
    hipMemsetAsync(cur, 0, (size_t)N * 4, stream);

    // CSR build
    {
        int blk = 256, g = (Etot + blk - 1) / blk;
        k_hist<<<g, blk, 0, stream>>>(ei, E, Etot, deg);
        k_scan<<<1, 1024, 0, stream>>>(deg, rs, N);
        k_fill<<<g, blk, 0, stream>>>(ei, E, Etot, rs, cur, csr_src);
    }

    // layer 1
    k_gemm1<<<(N + NPB - 1) / NPB, 512, 0, stream>>>(x, W1, asrc1w, adst1w, h1, asrc1, adst1, N);
    k_sm1<<<(N + 3) / 4, 256, 0, stream>>>(rs, csr_src, asrc1, adst1, aE1, N);
    k_agg1<<<N, 512, 0, stream>>>(rs, csr_src, aE1, h1, b1, y, N);

    // layer 2
    k_gemm2<<<512, 1024, 0, stream>>>(y, W2, asrc2w, adst2w, h2, asrc2, adst2, N);
    {
        int blk = 256, g = (N + blk - 1) / blk;
        k_sm2<<<g, blk, 0, stream>>>(rs, csr_src, asrc2, adst2, aE2, N);
    }
    k_out<<<(N + 3) / 4, 256, 0, stream>>>(rs, csr_src, aE2, h2, b2, out, N);
}

// Round 3
// 741.027 us; speedup vs baseline: 2.1827x; 1.0648x over previous
//
#include <hip/hip_runtime.h>
#include <hip/hip_bf16.h>
#include <math.h>

#define NEG_SLOPE 0.2f
typedef __hip_bfloat16 bf16;

__device__ __forceinline__ void edge_sd(const int* __restrict__ ei, int E, int e, int& s, int& d) {
    if (e < E) { s = ei[e]; d = ei[E + e]; }
    else { s = e - E; d = s; }  // self-loop
}

// ================= CSR build =================
__global__ void k_hist(const int* __restrict__ ei, int E, int Etot, int* __restrict__ deg)
{
    int e = blockIdx.x * blockDim.x + threadIdx.x;
    if (e >= Etot) return;
    int s, d; edge_sd(ei, E, e, s, d);
    atomicAdd(&deg[d], 1);
}

__global__ __launch_bounds__(1024) void k_scan(const int* __restrict__ deg,
                                               int* __restrict__ rs, int N)
{
    __shared__ int part[1024];
    int t = threadIdx.x;
    int chunk = (N + 1023) >> 10;
    int b = t * chunk, e = min(b + chunk, N);
    int s = 0;
    for (int i = b; i < e; ++i) s += deg[i];
    part[t] = s;
    __syncthreads();
    for (int off = 1; off < 1024; off <<= 1) {
        int v = (t >= off) ? part[t - off] : 0;
        __syncthreads();
        part[t] += v;
        __syncthreads();
    }
    int excl = (t == 0) ? 0 : part[t - 1];
    for (int i = b; i < e; ++i) { rs[i] = excl; excl += deg[i]; }
    if (t == 1023) rs[N] = part[1023];
}

__global__ void k_fill(const int* __restrict__ ei, int E, int Etot,
                       const int* __restrict__ rs, int* __restrict__ cur,
                       int* __restrict__ csr_src)
{
    int e = blockIdx.x * blockDim.x + threadIdx.x;
    if (e >= Etot) return;
    int s, d; edge_sd(ei, E, e, s, d);
    int pos = rs[d] + atomicAdd(&cur[d], 1);
    csr_src[pos] = s;
}

// ================= Layer 1 =================
// Fold W1 with attention vectors: wsrc/wdst[k][h] = sum_c W1[k, h*64+c] * a[h][c]
__global__ __launch_bounds__(512) void k_prew(
    const float* __restrict__ W1, const float* __restrict__ a_src,
    const float* __restrict__ a_dst, float* __restrict__ wsrc, float* __restrict__ wdst)
{
    int t = threadIdx.x;           // 512 = 64 k x 8 h
    int k = t >> 3, h = t & 7;
    float s = 0.f, d = 0.f;
    const float* wr = W1 + k * 512 + h * 64;
    const float* as = a_src + h * 64;
    const float* ad = a_dst + h * 64;
#pragma unroll
    for (int c = 0; c < 64; ++c) { s += wr[c] * as[c]; d += wr[c] * ad[c]; }
    wsrc[k * 8 + h] = s;
    wdst[k * 8 + h] = d;
}

// per-node attention terms: asrc[n,h] = x[n,:]·wsrc[:,h]  (wave per node, lane=k)
__global__ __launch_bounds__(256) void k_alpha1n(
    const float* __restrict__ x, const float* __restrict__ wsrc,
    const float* __restrict__ wdst, float* __restrict__ asrc,
    float* __restrict__ adst, int N)
{
    int node = blockIdx.x * 4 + (threadIdx.x >> 6);
    if (node >= N) return;
    int k = threadIdx.x & 63;
    float xv = x[(size_t)node * 64 + k];
#pragma unroll
    for (int h = 0; h < 8; ++h) {
        float s = xv * wsrc[k * 8 + h];
        float d = xv * wdst[k * 8 + h];
#pragma unroll
        for (int off = 1; off < 64; off <<= 1) {
            s += __shfl_xor(s, off, 64);
            d += __shfl_xor(d, off, 64);
        }
        if (k == 0) { asrc[node * 8 + h] = s; adst[node * 8 + h] = d; }
    }
}

// softmax layer1: wave per node; lane = (j0 = lane>>3, head = lane&7)
__global__ __launch_bounds__(256) void k_sm1(
    const int* __restrict__ rs, const int* __restrict__ csr_src,
    const float* __restrict__ asrc, const float* __restrict__ adst,
    float* __restrict__ aE, int N)
{
    int node = blockIdx.x * 4 + (threadIdx.x >> 6);
    if (node >= N) return;
    int lane = threadIdx.x & 63;
    int h = lane & 7, j0 = lane >> 3;
    int base = rs[node], deg = rs[node + 1] - base;
    float ad = adst[node * 8 + h];
    float m = -1e30f;
    for (int j = j0; j < deg; j += 8) {
        int s = csr_src[base + j];
        float el = asrc[s * 8 + h] + ad;
        el = el >= 0.f ? el : NEG_SLOPE * el;
        m = fmaxf(m, el);
    }
    m = fmaxf(m, __shfl_xor(m, 8, 64));
    m = fmaxf(m, __shfl_xor(m, 16, 64));
    m = fmaxf(m, __shfl_xor(m, 32, 64));
    float sum = 0.f;
    for (int j = j0; j < deg; j += 8) {
        int s = csr_src[base + j];
        float el = asrc[s * 8 + h] + ad;
        el = el >= 0.f ? el : NEG_SLOPE * el;
        float p = expf(el - m);
        sum += p;
        aE[(size_t)(base + j) * 8 + h] = p;
    }
    sum += __shfl_xor(sum, 8, 64);
    sum += __shfl_xor(sum, 16, 64);
    sum += __shfl_xor(sum, 32, 64);
    float inv = 1.f / (sum + 1e-16f);
    for (int j = j0; j < deg; j += 8) aE[(size_t)(base + j) * 8 + h] *= inv;
}

// aggregate in x-space: z[d][h][k] = sum_j alpha[j,h] * x[src_j][k]
// block(512) per node: thread = (h = t>>6, k = t&63); x row read is 256B coalesced
__global__ __launch_bounds__(512) void k_aggx(
    const int* __restrict__ rs, const int* __restrict__ csr_src,
    const float* __restrict__ aE, const float* __restrict__ x,
    bf16* __restrict__ z, int N)
{
    int d = blockIdx.x;
    int t = threadIdx.x;
    int h = t >> 6, k = t & 63;
    int base = rs[d], end = rs[d + 1];
    float acc = 0.f;
    int p = base;
    for (; p + 1 < end; p += 2) {
        int s0 = csr_src[p], s1 = csr_src[p + 1];
        float a0 = aE[(size_t)p * 8 + h];
        float a1 = aE[(size_t)(p + 1) * 8 + h];
        float x0 = x[(size_t)s0 * 64 + k];
        float x1 = x[(size_t)s1 * 64 + k];
        acc += a0 * x0 + a1 * x1;
    }
    if (p < end) {
        int s0 = csr_src[p];
        acc += aE[(size_t)p * 8 + h] * x[(size_t)s0 * 64 + k];
    }
    z[(size_t)d * 512 + t] = __float2bfloat16(acc);
}

// per-head GEMM: y[n, h*64+c2] = elu( sum_k z[n][h][k] * W1[k][h*64+c2] + b1 )
#define NPB 8
__global__ __launch_bounds__(512) void k_gemmz(
    const bf16* __restrict__ z, const float* __restrict__ W1,
    const float* __restrict__ b1, bf16* __restrict__ y, int N)
{
    int n0 = blockIdx.x * NPB;
    int t = threadIdx.x;
    __shared__ float zs[NPB][512];
#pragma unroll
    for (int m = 0; m < NPB; ++m) {
        int n = n0 + m;
        zs[m][t] = (n < N) ? __bfloat162float(z[(size_t)n * 512 + t]) : 0.f;
    }
    __syncthreads();
    int h = t >> 6;
    float acc[NPB];
#pragma unroll
    for (int m = 0; m < NPB; ++m) acc[m] = 0.f;
#pragma unroll 8
    for (int k = 0; k < 64; ++k) {
        float w = W1[k * 512 + t];
#pragma unroll
        for (int m = 0; m < NPB; ++m) acc[m] += zs[m][h * 64 + k] * w;
    }
    float bias = b1[t];
#pragma unroll
    for (int m = 0; m < NPB; ++m) {
        int n = n0 + m;
        if (n < N) {
            float v = acc[m] + bias;
            v = v > 0.f ? v : expf(v) - 1.f;
            y[(size_t)n * 512 + t] = __float2bfloat16(v);
        }
    }
}

// ================= Layer 2 =================
__global__ __launch_bounds__(1024) void k_gemm2(
    const bf16* __restrict__ y, const float* __restrict__ W2,
    const float* __restrict__ a_src2, const float* __restrict__ a_dst2,
    float* __restrict__ h2, float* __restrict__ asrc, float* __restrict__ adst, int N)
{
    __shared__ float W2t[17][512];
    int t = threadIdx.x;
    for (int i = t; i < 512 * 17; i += 1024) {
        int k = i / 17, c = i % 17;
        W2t[c][k] = W2[i];
    }
    __syncthreads();
    int wave = t >> 6, lane = t & 63;
    int stride = gridDim.x * 16;
    for (int n = blockIdx.x * 16 + wave; n < N; n += stride) {
        const bf16* yr = y + (size_t)n * 512;
        float yk[8];
#pragma unroll
        for (int i = 0; i < 8; ++i) yk[i] = __bfloat162float(yr[i * 64 + lane]);
        float acc[17];
#pragma unroll
        for (int c = 0; c < 17; ++c) {
            float a = 0.f;
#pragma unroll
            for (int i = 0; i < 8; ++i) a += yk[i] * W2t[c][i * 64 + lane];
            acc[c] = a;
        }
#pragma unroll
        for (int c = 0; c < 17; ++c) {
            float v = acc[c];
            v += __shfl_xor(v, 1, 64);  v += __shfl_xor(v, 2, 64);
            v += __shfl_xor(v, 4, 64);  v += __shfl_xor(v, 8, 64);
            v += __shfl_xor(v, 16, 64); v += __shfl_xor(v, 32, 64);
            acc[c] = v;
        }
        if (lane == 0) {
            float s = 0.f, d = 0.f;
#pragma unroll
            for (int c = 0; c < 17; ++c) {
                h2[(size_t)n * 17 + c] = acc[c];
                s += acc[c] * a_src2[c];
                d += acc[c] * a_dst2[c];
            }
            asrc[n] = s; adst[n] = d;
        }
    }
}

// softmax layer2: wave per node, lane = edge slot
__global__ __launch_bounds__(256) void k_sm2(
    const int* __restrict__ rs, const int* __restrict__ csr_src,
    const float* __restrict__ asrc, const float* __restrict__ adst,
    float* __restrict__ alpha, int N)
{
    int node = blockIdx.x * 4 + (threadIdx.x >> 6);
    if (node >= N) return;
    int lane = threadIdx.x & 63;
    int base = rs[node], deg = rs[node + 1] - base;
    float ad = adst[node];
    float m = -1e30f;
    for (int j = lane; j < deg; j += 64) {
        float el = asrc[csr_src[base + j]] + ad;
        el = el >= 0.f ? el : NEG_SLOPE * el;
        m = fmaxf(m, el);
    }
#pragma unroll
    for (int off = 1; off < 64; off <<= 1) m = fmaxf(m, __shfl_xor(m, off, 64));
    float sum = 0.f;
    for (int j = lane; j < deg; j += 64) {
        float el = asrc[csr_src[base + j]] + ad;
        el = el >= 0.f ? el : NEG_SLOPE * el;
        float p = expf(el - m);
        sum += p;
        alpha[base + j] = p;
    }
#pragma unroll
    for (int off = 1; off < 64; off <<= 1) sum += __shfl_xor(sum, off, 64);
    float inv = 1.f / (sum + 1e-16f);
    for (int j = lane; j < deg; j += 64) alpha[base + j] *= inv;
}

// aggregate layer2 + bias + log_softmax: wave per node, lanes 0..16 = channels
__global__ __launch_bounds__(256) void k_out(
    const int* __restrict__ rs, const int* __restrict__ csr_src,
    const float* __restrict__ alpha, const float* __restrict__ h2,
    const float* __restrict__ b2, float* __restrict__ out, int N)
{
    int node = blockIdx.x * 4 + (threadIdx.x >> 6);
    if (node >= N) return;
    int lane = threadIdx.x & 63;
    int base = rs[node], end = rs[node + 1];
    float acc = 0.f;
    if (lane < 17) {
        for (int p = base; p < end; ++p) {
            int s = csr_src[p];
            acc += alpha[p] * h2[(size_t)s * 17 + lane];
        }
    }
    float logit = (lane < 17) ? acc + b2[lane] : -1e30f;
    float m = logit;
#pragma unroll
    for (int off = 1; off < 64; off <<= 1) m = fmaxf(m, __shfl_xor(m, off, 64));
    float p = (lane < 17) ? expf(logit - m) : 0.f;
    float ssum = p;
#pragma unroll
    for (int off = 1; off < 64; off <<= 1) ssum += __shfl_xor(ssum, off, 64);
    if (lane < 17) out[(size_t)node * 17 + lane] = logit - m - logf(ssum);
}

extern "C" void kernel_launch(void* const* d_in, const int* in_sizes, int n_in,
                              void* d_out, int out_size, void* d_ws, size_t ws_size,
                              hipStream_t stream)
{
    const float* x      = (const float*)d_in[0];
    const int*   ei     = (const int*)d_in[1];
    const float* W1     = (const float*)d_in[2];
    const float* asrc1w = (const float*)d_in[3];
    const float* adst1w = (const float*)d_in[4];
    const float* b1     = (const float*)d_in[5];
    const float* W2     = (const float*)d_in[6];
    const float* asrc2w = (const float*)d_in[7];
    const float* adst2w = (const float*)d_in[8];
    const float* b2     = (const float*)d_in[9];
    float* out = (float*)d_out;

    const int N = in_sizes[0] / 64;
    const int E = in_sizes[1] / 2;
    const int Etot = N + E;

    // workspace layout
    float* ws = (float*)d_ws;
    size_t o = 0;
    bf16*  z     = (bf16*)(ws + o); o += (size_t)N * 256;   // N*512 bf16
    bf16*  y     = (bf16*)(ws + o); o += (size_t)N * 256;   // N*512 bf16
    float* wsrc  = ws + o; o += 512;
    float* wdst  = ws + o; o += 512;
    float* asrc1 = ws + o; o += (size_t)N * 8;
    float* adst1 = ws + o; o += (size_t)N * 8;
    float* aE1   = ws + o; o += (size_t)Etot * 8;
    float* h2    = ws + o; o += (size_t)N * 17;
    float* asrc2 = ws + o; o += (size_t)N;
    float* adst2 = ws + o; o += (size_t)N;
    float* aE2   = ws + o; o += (size_t)Etot;
    int* deg     = (int*)(ws + o); o += (size_t)N;
    int* cur     = (int*)(ws + o); o += (size_t)N;
    int* rs      = (int*)(ws + o); o += (size_t)N + 1;
    int* csr_src = (int*)(ws + o); o += (size_t)Etot;

    hipMemsetAsync(deg, 0, (size_t)N * 4, stream);
    hipMemsetAsync(cur, 0, (size_t)N * 4, stream);

    // CSR build
    {
        int blk = 256, g = (Etot + blk - 1) / blk;
        k_hist<<<g, blk, 0, stream>>>(ei, E, Etot, deg);
        k_scan<<<1, 1024, 0, stream>>>(deg, rs, N);
        k_fill<<<g, blk, 0, stream>>>(ei, E, Etot, rs, cur, csr_src);
    }

    // layer 1
    k_prew<<<1, 512, 0, stream>>>(W1, asrc1w, adst1w, wsrc, wdst);
    k_alpha1n<<<(N + 3) / 4, 256, 0, stream>>>(x, wsrc, wdst, asrc1, adst1, N);
    k_sm1<<<(N + 3) / 4, 256, 0, stream>>>(rs, csr_src, asrc1, adst1, aE1, N);
    k_aggx<<<N, 512, 0, stream>>>(rs, csr_src, aE1, x, z, N);
    k_gemmz<<<(N + NPB - 1) / NPB, 512, 0, stream>>>(z, W1, b1, y, N);

    // layer 2
    k_gemm2<<<512, 1024, 0, stream>>>(y, W2, asrc2w, adst2w, h2, asrc2, adst2, N);
    k_sm2<<<(N + 3) / 4, 256, 0, stream>>>(rs, csr_src, asrc2, adst2, aE2, N);
    k_out<<<(N + 3) / 4, 256, 0, stream>>>(rs, csr_src, aE2, h2, b2, out, N);
}

// Round 4
// 584.298 us; speedup vs baseline: 2.7681x; 1.2682x over previous
//
#include <hip/hip_runtime.h>
#include <hip/hip_bf16.h>
#include <math.h>

#define NEG_SLOPE 0.2f
typedef __hip_bfloat16 bf16;
typedef __attribute__((ext_vector_type(8))) unsigned short ushort8;

__device__ __forceinline__ float bf2f(unsigned short u) {
    return __uint_as_float(((unsigned)u) << 16);
}

__device__ __forceinline__ void edge_sd(const int* __restrict__ ei, int E, int e, int& s, int& d) {
    if (e < E) { s = ei[e]; d = ei[E + e]; }
    else { s = e - E; d = s; }  // self-loop
}

// ================= CSR build =================
__global__ void k_hist(const int* __restrict__ ei, int E, int Etot, int* __restrict__ deg)
{
    int e = blockIdx.x * blockDim.x + threadIdx.x;
    if (e >= Etot) return;
    int s, d; edge_sd(ei, E, e, s, d);
    atomicAdd(&deg[d], 1);
}

__global__ __launch_bounds__(1024) void k_scan(const int* __restrict__ deg,
                                               int* __restrict__ rs, int N)
{
    __shared__ int part[1024];
    int t = threadIdx.x;
    int chunk = (N + 1023) >> 10;
    int b = t * chunk, e = min(b + chunk, N);
    int s = 0;
    for (int i = b; i < e; ++i) s += deg[i];
    part[t] = s;
    __syncthreads();
    for (int off = 1; off < 1024; off <<= 1) {
        int v = (t >= off) ? part[t - off] : 0;
        __syncthreads();
        part[t] += v;
        __syncthreads();
    }
    int excl = (t == 0) ? 0 : part[t - 1];
    for (int i = b; i < e; ++i) { rs[i] = excl; excl += deg[i]; }
    if (t == 1023) rs[N] = part[1023];
}

__global__ void k_fill(const int* __restrict__ ei, int E, int Etot,
                       const int* __restrict__ rs, int* __restrict__ cur,
                       int* __restrict__ csr_src)
{
    int e = blockIdx.x * blockDim.x + threadIdx.x;
    if (e >= Etot) return;
    int s, d; edge_sd(ei, E, e, s, d);
    int pos = rs[d] + atomicAdd(&cur[d], 1);
    csr_src[pos] = s;
}

// ================= Layer 1 =================
// wboth[k][c16]: c<8 -> src-fold head c ; c>=8 -> dst-fold head c-8
__global__ __launch_bounds__(512) void k_prew(
    const float* __restrict__ W1, const float* __restrict__ a_src,
    const float* __restrict__ a_dst, float* __restrict__ wboth)
{
    int t = threadIdx.x;           // 512 = 64 k x 8 h
    int k = t >> 3, h = t & 7;
    float s = 0.f, d = 0.f;
    const float* wr = W1 + k * 512 + h * 64;
    const float* as = a_src + h * 64;
    const float* ad = a_dst + h * 64;
#pragma unroll
    for (int c = 0; c < 64; ++c) { s += wr[c] * as[c]; d += wr[c] * ad[c]; }
    wboth[k * 16 + h] = s;
    wboth[k * 16 + 8 + h] = d;
}

// per-node attention terms: 256 thr = 4 waves x 4 nodes x 16 lanes
__global__ __launch_bounds__(256) void k_alpha1n(
    const float* __restrict__ x, const float* __restrict__ wboth,
    float* __restrict__ asrc, float* __restrict__ adst, int N)
{
    __shared__ float wl[16][64];   // transposed: wl[c][k]
    int t = threadIdx.x;
    for (int i = t; i < 1024; i += 256) {
        int k = i >> 4, c = i & 15;
        wl[c][k] = wboth[i];
    }
    __syncthreads();
    int wave = t >> 6, lane = t & 63;
    int nsub = lane >> 4, ksub = lane & 15;
    int n = blockIdx.x * 16 + wave * 4 + nsub;
    bool valid = (n < N);
    float xv[4];
#pragma unroll
    for (int i = 0; i < 4; ++i)
        xv[i] = valid ? x[(size_t)n * 64 + i * 16 + ksub] : 0.f;
    float acc[16];
#pragma unroll
    for (int c = 0; c < 16; ++c) acc[c] = 0.f;
#pragma unroll
    for (int i = 0; i < 4; ++i) {
        float xi = xv[i];
        int k = i * 16 + ksub;
#pragma unroll
        for (int c = 0; c < 16; ++c) acc[c] += xi * wl[c][k];
    }
#pragma unroll
    for (int c = 0; c < 16; ++c) {
        acc[c] += __shfl_xor(acc[c], 1, 16);
        acc[c] += __shfl_xor(acc[c], 2, 16);
        acc[c] += __shfl_xor(acc[c], 4, 16);
        acc[c] += __shfl_xor(acc[c], 8, 16);
    }
    if (valid) {
        if (ksub < 8) asrc[n * 8 + ksub] = acc[ksub];
        else          adst[n * 8 + (ksub - 8)] = acc[ksub];
    }
}

// softmax layer1: wave per node; lane = (j0 = lane>>3, head = lane&7)
__global__ __launch_bounds__(256) void k_sm1(
    const int* __restrict__ rs, const int* __restrict__ csr_src,
    const float* __restrict__ asrc, const float* __restrict__ adst,
    float* __restrict__ aE, int N)
{
    int node = blockIdx.x * 4 + (threadIdx.x >> 6);
    if (node >= N) return;
    int lane = threadIdx.x & 63;
    int h = lane & 7, j0 = lane >> 3;
    int base = rs[node], deg = rs[node + 1] - base;
    float ad = adst[node * 8 + h];
    float m = -1e30f;
    for (int j = j0; j < deg; j += 8) {
        int s = csr_src[base + j];
        float el = asrc[s * 8 + h] + ad;
        el = el >= 0.f ? el : NEG_SLOPE * el;
        m = fmaxf(m, el);
    }
    m = fmaxf(m, __shfl_xor(m, 8, 64));
    m = fmaxf(m, __shfl_xor(m, 16, 64));
    m = fmaxf(m, __shfl_xor(m, 32, 64));
    float sum = 0.f;
    for (int j = j0; j < deg; j += 8) {
        int s = csr_src[base + j];
        float el = asrc[s * 8 + h] + ad;
        el = el >= 0.f ? el : NEG_SLOPE * el;
        float p = expf(el - m);
        sum += p;
        aE[(size_t)(base + j) * 8 + h] = p;
    }
    sum += __shfl_xor(sum, 8, 64);
    sum += __shfl_xor(sum, 16, 64);
    sum += __shfl_xor(sum, 32, 64);
    float inv = 1.f / (sum + 1e-16f);
    for (int j = j0; j < deg; j += 8) aE[(size_t)(base + j) * 8 + h] *= inv;
}

// aggregate in x-space: z[d][h][k] = sum_j alpha[j,h] * x[src_j][k]
__global__ __launch_bounds__(512) void k_aggx(
    const int* __restrict__ rs, const int* __restrict__ csr_src,
    const float* __restrict__ aE, const float* __restrict__ x,
    bf16* __restrict__ z, int N)
{
    int d = blockIdx.x;
    int t = threadIdx.x;
    int h = t >> 6, k = t & 63;
    int base = rs[d], end = rs[d + 1];
    float acc = 0.f;
    int p = base;
    for (; p + 3 < end; p += 4) {
        int s0 = csr_src[p],     s1 = csr_src[p + 1];
        int s2 = csr_src[p + 2], s3 = csr_src[p + 3];
        float a0 = aE[(size_t)p * 8 + h];
        float a1 = aE[(size_t)(p + 1) * 8 + h];
        float a2 = aE[(size_t)(p + 2) * 8 + h];
        float a3 = aE[(size_t)(p + 3) * 8 + h];
        float x0 = x[(size_t)s0 * 64 + k];
        float x1 = x[(size_t)s1 * 64 + k];
        float x2 = x[(size_t)s2 * 64 + k];
        float x3 = x[(size_t)s3 * 64 + k];
        acc += a0 * x0 + a1 * x1 + a2 * x2 + a3 * x3;
    }
    for (; p < end; ++p) {
        int s0 = csr_src[p];
        acc += aE[(size_t)p * 8 + h] * x[(size_t)s0 * 64 + k];
    }
    z[(size_t)d * 512 + t] = __float2bfloat16(acc);
}

// per-head GEMM: y[n, h*64+c2] = elu( sum_k z[n][h][k] * W1[k][h*64+c2] + b1 )
#define NPB 8
__global__ __launch_bounds__(512) void k_gemmz(
    const bf16* __restrict__ z, const float* __restrict__ W1,
    const float* __restrict__ b1, bf16* __restrict__ y, int N)
{
    int n0 = blockIdx.x * NPB;
    int t = threadIdx.x;
    __shared__ float zs[NPB][512];
    {
        // thread t loads 8 consecutive bf16 = 16B (fully coalesced)
        int e = t * 8;
        int m = e >> 9, col = e & 511;
        int n = n0 + m;
        if (n < N) {
            ushort8 u = *(const ushort8*)(z + (size_t)n * 512 + col);
#pragma unroll
            for (int j = 0; j < 8; ++j) zs[m][col + j] = bf2f(u[j]);
        } else {
#pragma unroll
            for (int j = 0; j < 8; ++j) zs[m][col + j] = 0.f;
        }
    }
    __syncthreads();
    int h = t >> 6;
    float acc[NPB];
#pragma unroll
    for (int m = 0; m < NPB; ++m) acc[m] = 0.f;
#pragma unroll 8
    for (int k = 0; k < 64; ++k) {
        float w = W1[k * 512 + t];
#pragma unroll
        for (int m = 0; m < NPB; ++m) acc[m] += zs[m][h * 64 + k] * w;
    }
    float bias = b1[t];
#pragma unroll
    for (int m = 0; m < NPB; ++m) {
        int n = n0 + m;
        if (n < N) {
            float v = acc[m] + bias;
            v = v > 0.f ? v : expf(v) - 1.f;
            y[(size_t)n * 512 + t] = __float2bfloat16(v);
        }
    }
}

// ================= Layer 2 =================
// h2 = y @ W2 (+ fused attention dots). 512 thr = 8 waves x 4 nodes x 16 lanes.
__global__ __launch_bounds__(512) void k_gemm2(
    const bf16* __restrict__ y, const float* __restrict__ W2,
    const float* __restrict__ a_src2, const float* __restrict__ a_dst2,
    float* __restrict__ h2, float* __restrict__ asrc, float* __restrict__ adst, int N)
{
    __shared__ float W2t[17][512];
    __shared__ float a2s[34];
    int t = threadIdx.x;
    for (int i = t; i < 17 * 512; i += 512) {
        int c = i >> 9, k = i & 511;
        W2t[c][k] = W2[k * 17 + c];
    }
    if (t < 17) a2s[t] = a_src2[t];
    else if (t < 34) a2s[t] = a_dst2[t - 17];
    __syncthreads();

    int wave = t >> 6, lane = t & 63;
    int nsub = lane >> 4, ksub = lane & 15;
    int n = blockIdx.x * 32 + wave * 4 + nsub;
    bool valid = (n < N);

    float yk[32];
    if (valid) {
        const ushort8* yr = (const ushort8*)(y + (size_t)n * 512 + ksub * 32);
#pragma unroll
        for (int v = 0; v < 4; ++v) {
            ushort8 u = yr[v];
#pragma unroll
            for (int j = 0; j < 8; ++j) yk[v * 8 + j] = bf2f(u[j]);
        }
    } else {
#pragma unroll
        for (int i = 0; i < 32; ++i) yk[i] = 0.f;
    }

    float acc[17];
#pragma unroll
    for (int c = 0; c < 17; ++c) {
        const float4* wr = (const float4*)&W2t[c][ksub * 32];
        float a = 0.f;
#pragma unroll
        for (int v = 0; v < 8; ++v) {
            float4 w = wr[v];
            a += yk[v * 4 + 0] * w.x + yk[v * 4 + 1] * w.y
               + yk[v * 4 + 2] * w.z + yk[v * 4 + 3] * w.w;
        }
        acc[c] = a;
    }
    // width-16 butterfly: all 16 lanes of the group end with the full sums
#pragma unroll
    for (int c = 0; c < 17; ++c) {
        acc[c] += __shfl_xor(acc[c], 1, 16);
        acc[c] += __shfl_xor(acc[c], 2, 16);
        acc[c] += __shfl_xor(acc[c], 4, 16);
        acc[c] += __shfl_xor(acc[c], 8, 16);
    }
    if (valid) {
        if (ksub < 16) h2[(size_t)n * 17 + ksub] = acc[ksub];
        if (ksub == 0) h2[(size_t)n * 17 + 16] = acc[16];
        if (ksub == 1) {
            float s = 0.f;
#pragma unroll
            for (int c = 0; c < 17; ++c) s += acc[c] * a2s[c];
            asrc[n] = s;
        }
        if (ksub == 2) {
            float d = 0.f;
#pragma unroll
            for (int c = 0; c < 17; ++c) d += acc[c] * a2s[17 + c];
            adst[n] = d;
        }
    }
}

// softmax layer2: wave per node, lane = edge slot
__global__ __launch_bounds__(256) void k_sm2(
    const int* __restrict__ rs, const int* __restrict__ csr_src,
    const float* __restrict__ asrc, const float* __restrict__ adst,
    float* __restrict__ alpha, int N)
{
    int node = blockIdx.x * 4 + (threadIdx.x >> 6);
    if (node >= N) return;
    int lane = threadIdx.x & 63;
    int base = rs[node], deg = rs[node + 1] - base;
    float ad = adst[node];
    float m = -1e30f;
    for (int j = lane; j < deg; j += 64) {
        float el = asrc[csr_src[base + j]] + ad;
        el = el >= 0.f ? el : NEG_SLOPE * el;
        m = fmaxf(m, el);
    }
#pragma unroll
    for (int off = 1; off < 64; off <<= 1) m = fmaxf(m, __shfl_xor(m, off, 64));
    float sum = 0.f;
    for (int j = lane; j < deg; j += 64) {
        float el = asrc[csr_src[base + j]] + ad;
        el = el >= 0.f ? el : NEG_SLOPE * el;
        float p = expf(el - m);
        sum += p;
        alpha[base + j] = p;
    }
#pragma unroll
    for (int off = 1; off < 64; off <<= 1) sum += __shfl_xor(sum, off, 64);
    float inv = 1.f / (sum + 1e-16f);
    for (int j = lane; j < deg; j += 64) alpha[base + j] *= inv;
}

// aggregate layer2 + bias + log_softmax: wave per node; lane = (jsub = lane>>5, c = lane&31)
__global__ __launch_bounds__(256) void k_out(
    const int* __restrict__ rs, const int* __restrict__ csr_src,
    const float* __restrict__ alpha, const float* __restrict__ h2,
    const float* __restrict__ b2, float* __restrict__ out, int N)
{
    int node = blockIdx.x * 4 + (threadIdx.x >> 6);
    if (node >= N) return;
    int lane = threadIdx.x & 63;
    int c = lane & 31, jsub = lane >> 5;
    int base = rs[node], end = rs[node + 1];
    float acc = 0.f;
    if (c < 17) {
        for (int p = base + jsub; p < end; p += 2) {
            int s = csr_src[p];
            acc += alpha[p] * h2[(size_t)s * 17 + c];
        }
    }
    acc += __shfl_xor(acc, 32, 64);  // combine the two edge halves
    float logit = (c < 17) ? acc + b2[c] : -1e30f;
    float m = logit;
#pragma unroll
    for (int off = 1; off < 32; off <<= 1) m = fmaxf(m, __shfl_xor(m, off, 32));
    float p = (c < 17) ? expf(logit - m) : 0.f;
    float ssum = p;
#pragma unroll
    for (int off = 1; off < 32; off <<= 1) ssum += __shfl_xor(ssum, off, 32);
    if (c < 17 && jsub == 0) out[(size_t)node * 17 + c] = logit - m - logf(ssum);
}

extern "C" void kernel_launch(void* const* d_in, const int* in_sizes, int n_in,
                              void* d_out, int out_size, void* d_ws, size_t ws_size,
                              hipStream_t stream)
{
    const float* x      = (const float*)d_in[0];
    const int*   ei     = (const int*)d_in[1];
    const float* W1     = (const float*)d_in[2];
    const float* asrc1w = (const float*)d_in[3];
    const float* adst1w = (const float*)d_in[4];
    const float* b1     = (const float*)d_in[5];
    const float* W2     = (const float*)d_in[6];
    const float* asrc2w = (const float*)d_in[7];
    const float* adst2w = (const float*)d_in[8];
    const float* b2     = (const float*)d_in[9];
    float* out = (float*)d_out;

    const int N = in_sizes[0] / 64;
    const int E = in_sizes[1] / 2;
    const int Etot = N + E;

    // workspace layout
    float* ws = (float*)d_ws;
    size_t o = 0;
    bf16*  z     = (bf16*)(ws + o); o += (size_t)N * 256;   // N*512 bf16
    bf16*  y     = (bf16*)(ws + o); o += (size_t)N * 256;   // N*512 bf16
    float* wboth = ws + o; o += 1024;
    float* asrc1 = ws + o; o += (size_t)N * 8;
    float* adst1 = ws + o; o += (size_t)N * 8;
    float* aE1   = ws + o; o += (size_t)Etot * 8;
    float* h2    = ws + o; o += (size_t)N * 17;
    float* asrc2 = ws + o; o += (size_t)N;
    float* adst2 = ws + o; o += (size_t)N;
    float* aE2   = ws + o; o += (size_t)Etot;
    int* deg     = (int*)(ws + o); o += (size_t)N;
    int* cur     = (int*)(ws + o); o += (size_t)N;
    int* rs      = (int*)(ws + o); o += (size_t)N + 1;
    int* csr_src = (int*)(ws + o); o += (size_t)Etot;

    hipMemsetAsync(deg, 0, (size_t)N * 4, stream);
    hipMemsetAsync(cur, 0, (size_t)N * 4, stream);

    // CSR build
    {
        int blk = 256, g = (Etot + blk - 1) / blk;
        k_hist<<<g, blk, 0, stream>>>(ei, E, Etot, deg);
        k_scan<<<1, 1024, 0, stream>>>(deg, rs, N);
        k_fill<<<g, blk, 0, stream>>>(ei, E, Etot, rs, cur, csr_src);
    }

    // layer 1
    k_prew<<<1, 512, 0, stream>>>(W1, asrc1w, adst1w, wboth);
    k_alpha1n<<<(N + 15) / 16, 256, 0, stream>>>(x, wboth, asrc1, adst1, N);
    k_sm1<<<(N + 3) / 4, 256, 0, stream>>>(rs, csr_src, asrc1, adst1, aE1, N);
    k_aggx<<<N, 512, 0, stream>>>(rs, csr_src, aE1, x, z, N);
    k_gemmz<<<(N + NPB - 1) / NPB, 512, 0, stream>>>(z, W1, b1, y, N);

    // layer 2
    k_gemm2<<<(N + 31) / 32, 512, 0, stream>>>(y, W2, asrc2w, adst2w, h2, asrc2, adst2, N);
    k_sm2<<<(N + 3) / 4, 256, 0, stream>>>(rs, csr_src, asrc2, adst2, aE2, N);
    k_out<<<(N + 3) / 4, 256, 0, stream>>>(rs, csr_src, aE2, h2, b2, out, N);
}